// Round 2
// baseline (1174.492 us; speedup 1.0000x reference)
//
#include <hip/hip_runtime.h>

#define FDIM 64
#define NB 32   // nodes per transform block

// One wave (64 lanes) per edge: lane f handles feature f.
// Gathers x[src] (coalesced 256B) and atomically accumulates into out[dst] at col_off.
// Lane 0 bumps the degree counter.
__global__ __launch_bounds__(256) void scatter_kernel(
    const int* __restrict__ ei, int E,
    const float* __restrict__ x,
    float* __restrict__ out, int col_off,
    float* __restrict__ cnt)
{
    long long gid = (long long)blockIdx.x * 256 + threadIdx.x;
    int e = (int)(gid >> 6);
    if (e >= E) return;
    int f = (int)(gid & 63);
    int s = ei[e];        // src row
    int d = ei[E + e];    // dst row
    float v = x[s * FDIM + f];
    atomicAdd(&out[d * 128 + col_off + f], v);
    if (f == 0) atomicAdd(&cnt[d], 1.0f);
}

// Per block: 32 nodes. LDS-staged weights (transposed) + node features.
// out rows are read (agg sums), scaled by 1/max(cnt,1), projected, and
// overwritten in place with the final result.
__global__ __launch_bounds__(256) void transform_kernel(
    const float* __restrict__ x,
    const float* __restrict__ Wp, const float* __restrict__ Wpc, const float* __restrict__ bp,
    const float* __restrict__ Wn, const float* __restrict__ Wnc, const float* __restrict__ bn,
    const float* __restrict__ cnt,   // [2*N]: pos counts then neg counts
    int N,
    float* __restrict__ out)
{
    // h=0 (pos) consumes B rows 0..127   = [aggp ; x]   -> V[0] = [Wp  ; Wpc]
    // h=1 (neg) consumes B rows 64..191  = [x ; aggn]   -> V[1] = [Wnc ; Wn ]
    __shared__ float V[2][128][64];      // 64 KB
    __shared__ float B[192][NB + 4];     // rows 0..63: aggp*sp; 64..127: x; 128..191: aggn*sn
    __shared__ float bias[128];

    int t = threadIdx.x;
    int node0 = blockIdx.x * NB;

    // Load + transpose the four 64x64 weight matrices into LDS.
    for (int i = t; i < 4096; i += 256) {
        int k = i >> 6, j = i & 63;
        V[0][k][j]      = Wp[j * 64 + k];
        V[0][64 + k][j] = Wpc[j * 64 + k];
        V[1][k][j]      = Wnc[j * 64 + k];   // pairs with x rows
        V[1][64 + k][j] = Wn[j * 64 + k];    // pairs with agg_neg rows
    }
    if (t < 64) { bias[t] = bp[t]; bias[64 + t] = bn[t]; }

    // Stage node features: coalesced global reads (k fastest across lanes).
    for (int i = t; i < 64 * NB; i += 256) {
        int k = i & 63, n = i >> 6;
        int node = node0 + n;
        if (node < N) {
            float sp = 1.0f / fmaxf(cnt[node], 1.0f);
            float sn = 1.0f / fmaxf(cnt[N + node], 1.0f);
            B[k][n]       = out[node * 128 + k] * sp;        // agg_pos mean
            B[64 + k][n]  = x[node * 64 + k];                // x
            B[128 + k][n] = out[node * 128 + 64 + k] * sn;   // agg_neg mean
        }
    }
    __syncthreads();

    // Register tile: 4 consecutive nodes x 2 consecutive j, per half.
    int jj = t & 31;    // j base = 2*jj
    int nq = t >> 5;    // n base = 4*nq  (0..7 -> covers 32 nodes)
    float acc[2][4][2];
    #pragma unroll
    for (int h = 0; h < 2; ++h)
        #pragma unroll
        for (int i = 0; i < 4; ++i) { acc[h][i][0] = 0.f; acc[h][i][1] = 0.f; }

    #pragma unroll
    for (int h = 0; h < 2; ++h) {
        int browbase = h * 64;   // pos reads B rows 0..127, neg reads 64..191
        #pragma unroll 4
        for (int kk = 0; kk < 128; ++kk) {
            float2 v = *(const float2*)&V[h][kk][2 * jj];
            float4 b = *(const float4*)&B[browbase + kk][4 * nq];
            acc[h][0][0] += b.x * v.x;  acc[h][0][1] += b.x * v.y;
            acc[h][1][0] += b.y * v.x;  acc[h][1][1] += b.y * v.y;
            acc[h][2][0] += b.z * v.x;  acc[h][2][1] += b.z * v.y;
            acc[h][3][0] += b.w * v.x;  acc[h][3][1] += b.w * v.y;
        }
    }

    // Write final output in place (this block's rows only; staged before sync).
    #pragma unroll
    for (int h = 0; h < 2; ++h) {
        float bx = bias[h * 64 + 2 * jj];
        float by = bias[h * 64 + 2 * jj + 1];
        #pragma unroll
        for (int i = 0; i < 4; ++i) {
            int node = node0 + 4 * nq + i;
            if (node < N) {
                float2 r;
                r.x = acc[h][i][0] + bx;
                r.y = acc[h][i][1] + by;
                *(float2*)&out[(long long)node * 128 + h * 64 + 2 * jj] = r;
            }
        }
    }
}

extern "C" void kernel_launch(void* const* d_in, const int* in_sizes, int n_in,
                              void* d_out, int out_size, void* d_ws, size_t ws_size,
                              hipStream_t stream) {
    const float* x   = (const float*)d_in[0];
    const int*   pei = (const int*)d_in[1];
    const int*   nei = (const int*)d_in[2];
    const float* Wp  = (const float*)d_in[3];
    const float* Wpc = (const float*)d_in[4];
    const float* bp  = (const float*)d_in[5];
    const float* Wn  = (const float*)d_in[6];
    const float* Wnc = (const float*)d_in[7];
    const float* bn  = (const float*)d_in[8];
    float* out = (float*)d_out;
    float* cnt = (float*)d_ws;   // [2*N] floats

    int N = in_sizes[0] / FDIM;
    int E = in_sizes[1] / 2;

    hipMemsetAsync(d_out, 0, (size_t)out_size * sizeof(float), stream);
    hipMemsetAsync(d_ws, 0, (size_t)2 * N * sizeof(float), stream);

    int sblocks = (int)(((long long)E * 64 + 255) / 256);
    scatter_kernel<<<sblocks, 256, 0, stream>>>(pei, E, x, out, 0, cnt);
    scatter_kernel<<<sblocks, 256, 0, stream>>>(nei, E, x, out, 64, cnt + N);

    int tblocks = (N + NB - 1) / NB;
    transform_kernel<<<tblocks, 256, 0, stream>>>(x, Wp, Wpc, bp, Wn, Wnc, bn,
                                                  cnt, N, out);
}

// Round 3
// 861.290 us; speedup vs baseline: 1.3636x; 1.3636x over previous
//
#include <hip/hip_runtime.h>

#define FDIM 64
#define NB 32   // nodes per transform block

// ================= sorted-aggregation pipeline (no f32 atomics) =============

// Histogram of destination nodes. cnt must be zeroed. One thread per edge.
__global__ __launch_bounds__(256) void hist_kernel(
    const int* __restrict__ ei, int E, int* __restrict__ cnt)
{
    int e = blockIdx.x * 256 + threadIdx.x;
    if (e < E) atomicAdd(&cnt[ei[E + e]], 1);
}

// Exclusive scan over n counters, 1024 elems/block (256 thr x 4).
__global__ __launch_bounds__(256) void scan_partial_kernel(
    const int* __restrict__ cnt, int n, int* __restrict__ bsums)
{
    __shared__ int s[256];
    int t = threadIdx.x;
    int i0 = blockIdx.x * 1024 + t * 4;
    int e0 = (i0 + 0 < n) ? cnt[i0 + 0] : 0;
    int e1 = (i0 + 1 < n) ? cnt[i0 + 1] : 0;
    int e2 = (i0 + 2 < n) ? cnt[i0 + 2] : 0;
    int e3 = (i0 + 3 < n) ? cnt[i0 + 3] : 0;
    s[t] = e0 + e1 + e2 + e3;
    __syncthreads();
    for (int d = 128; d > 0; d >>= 1) {
        if (t < d) s[t] += s[t + d];
        __syncthreads();
    }
    if (t == 0) bsums[blockIdx.x] = s[0];
}

__global__ void scan_bsums_kernel(int* __restrict__ bsums, int nb)
{
    if (threadIdx.x == 0 && blockIdx.x == 0) {
        int run = 0;
        for (int i = 0; i < nb; ++i) { int v = bsums[i]; bsums[i] = run; run += v; }
    }
}

__global__ __launch_bounds__(256) void scan_final_kernel(
    const int* __restrict__ cnt, int n, const int* __restrict__ bsums,
    int* __restrict__ offs, int* __restrict__ cursor)
{
    __shared__ int s[256];
    int t = threadIdx.x;
    int i0 = blockIdx.x * 1024 + t * 4;
    int e0 = (i0 + 0 < n) ? cnt[i0 + 0] : 0;
    int e1 = (i0 + 1 < n) ? cnt[i0 + 1] : 0;
    int e2 = (i0 + 2 < n) ? cnt[i0 + 2] : 0;
    int e3 = (i0 + 3 < n) ? cnt[i0 + 3] : 0;
    int mysum = e0 + e1 + e2 + e3;
    s[t] = mysum;
    __syncthreads();
    // Hillis-Steele inclusive scan over 256 thread sums
    for (int d = 1; d < 256; d <<= 1) {
        int v = (t >= d) ? s[t - d] : 0;
        __syncthreads();
        s[t] += v;
        __syncthreads();
    }
    int base = bsums[blockIdx.x] + (s[t] - mysum);
    int o0 = base, o1 = base + e0, o2 = o1 + e1, o3 = o2 + e2;
    if (i0 + 0 < n) { offs[i0 + 0] = o0; cursor[i0 + 0] = o0; }
    if (i0 + 1 < n) { offs[i0 + 1] = o1; cursor[i0 + 1] = o1; }
    if (i0 + 2 < n) { offs[i0 + 2] = o2; cursor[i0 + 2] = o2; }
    if (i0 + 3 < n) { offs[i0 + 3] = o3; cursor[i0 + 3] = o3; }
}

// Place src ids into per-dst contiguous slots. cursor pre-loaded with offsets.
__global__ __launch_bounds__(256) void place_kernel(
    const int* __restrict__ ei, int E, int* __restrict__ cursor,
    int* __restrict__ ss)
{
    int e = blockIdx.x * 256 + threadIdx.x;
    if (e < E) {
        int d = ei[E + e];
        int slot = atomicAdd(&cursor[d], 1);
        ss[slot] = ei[e];
    }
}

// One wave per (node, graph-half): walk the contiguous src list, gather x rows
// (coalesced 256B/edge), accumulate one feature per lane, write the mean once.
__global__ __launch_bounds__(256) void agg_kernel(
    const int* __restrict__ ss, const int* __restrict__ offs,
    const int* __restrict__ cnt, const float* __restrict__ x,
    int N, float* __restrict__ out)
{
    int w = blockIdx.x * 4 + (threadIdx.x >> 6);
    int lane = threadIdx.x & 63;
    if (w >= 2 * N) return;
    int node = (w < N) ? w : (w - N);
    int half = (w < N) ? 0 : 1;
    int o0 = offs[w];
    int deg = cnt[w];
    int o1 = o0 + deg;

    float acc = 0.f;
    int i = o0;
    for (; i + 4 <= o1; i += 4) {
        int s0 = ss[i], s1 = ss[i + 1], s2 = ss[i + 2], s3 = ss[i + 3];
        float a = x[s0 * FDIM + lane];
        float b = x[s1 * FDIM + lane];
        float c = x[s2 * FDIM + lane];
        float d = x[s3 * FDIM + lane];
        acc += a; acc += b; acc += c; acc += d;
    }
    for (; i < o1; ++i) acc += x[ss[i] * FDIM + lane];

    out[(long long)node * 128 + half * 64 + lane] = acc / fmaxf((float)deg, 1.f);
}

// ================= fallback scatter path (if ws too small) ==================

__global__ __launch_bounds__(256) void scatter_kernel(
    const int* __restrict__ ei, int E,
    const float* __restrict__ x,
    float* __restrict__ out, int col_off,
    float* __restrict__ cnt)
{
    long long gid = (long long)blockIdx.x * 256 + threadIdx.x;
    int e = (int)(gid >> 6);
    if (e >= E) return;
    int f = (int)(gid & 63);
    int s = ei[e];
    int d = ei[E + e];
    float v = x[s * FDIM + f];
    atomicAdd(&out[d * 128 + col_off + f], v);
    if (f == 0) atomicAdd(&cnt[d], 1.0f);
}

__global__ __launch_bounds__(256) void scale_kernel(
    float* __restrict__ out, const float* __restrict__ cnt, int N)
{
    int idx = blockIdx.x * 256 + threadIdx.x;
    if (idx >= N * 128) return;
    int node = idx >> 7, col = idx & 127, half = col >> 6;
    out[idx] /= fmaxf(cnt[half * N + node], 1.f);
}

// ================= transform: out = [aggp|x]@Vp + [x|aggn]@Vn + bias ========
// (agg columns of `out` already hold the MEAN.)
__global__ __launch_bounds__(256) void transform_kernel(
    const float* __restrict__ x,
    const float* __restrict__ Wp, const float* __restrict__ Wpc, const float* __restrict__ bp,
    const float* __restrict__ Wn, const float* __restrict__ Wnc, const float* __restrict__ bn,
    int N,
    float* __restrict__ out)
{
    // h=0 (pos) consumes B rows 0..127   = [aggp ; x]   -> V[0] = [Wp  ; Wpc]
    // h=1 (neg) consumes B rows 64..191  = [x ; aggn]   -> V[1] = [Wnc ; Wn ]
    __shared__ float V[2][128][64];      // 64 KB
    __shared__ float B[192][NB + 4];
    __shared__ float bias[128];

    int t = threadIdx.x;
    int node0 = blockIdx.x * NB;

    for (int i = t; i < 4096; i += 256) {
        int k = i >> 6, j = i & 63;
        V[0][k][j]      = Wp[j * 64 + k];
        V[0][64 + k][j] = Wpc[j * 64 + k];
        V[1][k][j]      = Wnc[j * 64 + k];   // pairs with x rows
        V[1][64 + k][j] = Wn[j * 64 + k];    // pairs with agg_neg rows
    }
    if (t < 64) { bias[t] = bp[t]; bias[64 + t] = bn[t]; }

    for (int i = t; i < 64 * NB; i += 256) {
        int k = i & 63, n = i >> 6;
        int node = node0 + n;
        if (node < N) {
            B[k][n]       = out[(long long)node * 128 + k];        // agg_pos mean
            B[64 + k][n]  = x[node * 64 + k];                      // x
            B[128 + k][n] = out[(long long)node * 128 + 64 + k];   // agg_neg mean
        }
    }
    __syncthreads();

    int jj = t & 31;
    int nq = t >> 5;
    float acc[2][4][2];
    #pragma unroll
    for (int h = 0; h < 2; ++h)
        #pragma unroll
        for (int i = 0; i < 4; ++i) { acc[h][i][0] = 0.f; acc[h][i][1] = 0.f; }

    #pragma unroll
    for (int h = 0; h < 2; ++h) {
        int browbase = h * 64;
        #pragma unroll 4
        for (int kk = 0; kk < 128; ++kk) {
            float2 v = *(const float2*)&V[h][kk][2 * jj];
            float4 b = *(const float4*)&B[browbase + kk][4 * nq];
            acc[h][0][0] += b.x * v.x;  acc[h][0][1] += b.x * v.y;
            acc[h][1][0] += b.y * v.x;  acc[h][1][1] += b.y * v.y;
            acc[h][2][0] += b.z * v.x;  acc[h][2][1] += b.z * v.y;
            acc[h][3][0] += b.w * v.x;  acc[h][3][1] += b.w * v.y;
        }
    }

    #pragma unroll
    for (int h = 0; h < 2; ++h) {
        float bx = bias[h * 64 + 2 * jj];
        float by = bias[h * 64 + 2 * jj + 1];
        #pragma unroll
        for (int i = 0; i < 4; ++i) {
            int node = node0 + 4 * nq + i;
            if (node < N) {
                float2 r;
                r.x = acc[h][i][0] + bx;
                r.y = acc[h][i][1] + by;
                *(float2*)&out[(long long)node * 128 + h * 64 + 2 * jj] = r;
            }
        }
    }
}

extern "C" void kernel_launch(void* const* d_in, const int* in_sizes, int n_in,
                              void* d_out, int out_size, void* d_ws, size_t ws_size,
                              hipStream_t stream) {
    const float* x   = (const float*)d_in[0];
    const int*   pei = (const int*)d_in[1];
    const int*   nei = (const int*)d_in[2];
    const float* Wp  = (const float*)d_in[3];
    const float* Wpc = (const float*)d_in[4];
    const float* bp  = (const float*)d_in[5];
    const float* Wn  = (const float*)d_in[6];
    const float* Wnc = (const float*)d_in[7];
    const float* bn  = (const float*)d_in[8];
    float* out = (float*)d_out;

    int N = in_sizes[0] / FDIM;
    int E = in_sizes[1] / 2;
    int n2 = 2 * N;
    int nb = (n2 + 1023) / 1024;

    size_t need = (size_t)(3 * n2 + 4096 + 2 * E) * sizeof(int);

    if (ws_size >= need && nb <= 4096) {
        int* cnt    = (int*)d_ws;
        int* offs   = cnt + n2;
        int* cursor = offs + n2;
        int* bsums  = cursor + n2;
        int* ss     = bsums + 4096;

        hipMemsetAsync(cnt, 0, (size_t)n2 * sizeof(int), stream);

        int eblocks = (E + 255) / 256;
        hist_kernel<<<eblocks, 256, 0, stream>>>(pei, E, cnt);
        hist_kernel<<<eblocks, 256, 0, stream>>>(nei, E, cnt + N);

        scan_partial_kernel<<<nb, 256, 0, stream>>>(cnt, n2, bsums);
        scan_bsums_kernel<<<1, 64, 0, stream>>>(bsums, nb);
        scan_final_kernel<<<nb, 256, 0, stream>>>(cnt, n2, bsums, offs, cursor);

        place_kernel<<<eblocks, 256, 0, stream>>>(pei, E, cursor, ss);
        place_kernel<<<eblocks, 256, 0, stream>>>(nei, E, cursor + N, ss);

        int ablocks = (n2 + 3) / 4;
        agg_kernel<<<ablocks, 256, 0, stream>>>(ss, offs, cnt, x, N, out);
    } else {
        // fallback: atomic scatter
        float* cntf = (float*)d_ws;
        hipMemsetAsync(d_out, 0, (size_t)out_size * sizeof(float), stream);
        hipMemsetAsync(d_ws, 0, (size_t)n2 * sizeof(float), stream);
        int sblocks = (int)(((long long)E * 64 + 255) / 256);
        scatter_kernel<<<sblocks, 256, 0, stream>>>(pei, E, x, out, 0, cntf);
        scatter_kernel<<<sblocks, 256, 0, stream>>>(nei, E, x, out, 64, cntf + N);
        scale_kernel<<<(N * 128 + 255) / 256, 256, 0, stream>>>(out, cntf, N);
    }

    int tblocks = (N + NB - 1) / NB;
    transform_kernel<<<tblocks, 256, 0, stream>>>(x, Wp, Wpc, bp, Wn, Wnc, bn,
                                                  N, out);
}

// Round 4
// 663.227 us; speedup vs baseline: 1.7709x; 1.2986x over previous
//
#include <hip/hip_runtime.h>

#define FDIM 64
#define NB 32

typedef __attribute__((ext_vector_type(8))) short short8;
typedef __attribute__((ext_vector_type(4))) float f32x4;

__device__ __forceinline__ ushort f2bf(float f) {
    unsigned u = __float_as_uint(f);
    unsigned r = (u + 0x7FFF + ((u >> 16) & 1)) >> 16;   // RNE
    return (ushort)r;
}
__device__ __forceinline__ float b2f(ushort s) {
    return __uint_as_float(((unsigned)s) << 16);
}

// ============ prep: x (f32) -> U[:,64:128) (bf16). U rows are 192 bf16. =====
__global__ __launch_bounds__(256) void prep_kernel(
    const float* __restrict__ x, int N, ushort* __restrict__ U)
{
    int i4 = (blockIdx.x * 256 + threadIdx.x) * 4;
    if (i4 >= N * 64) return;
    float4 f = *(const float4*)&x[i4];
    int node = i4 >> 6, c = i4 & 63;
    ushort4 s;
    s.x = f2bf(f.x); s.y = f2bf(f.y); s.z = f2bf(f.z); s.w = f2bf(f.w);
    *(ushort4*)&U[(size_t)node * 192 + 64 + c] = s;
}

// ============ histogram over BOTH edge lists ================================
__global__ __launch_bounds__(256) void hist2_kernel(
    const int* __restrict__ pei, const int* __restrict__ nei, int E,
    int* __restrict__ cnt, int N)
{
    int i = blockIdx.x * 256 + threadIdx.x;
    if (i < E)          atomicAdd(&cnt[pei[E + i]], 1);
    else if (i < 2 * E) atomicAdd(&cnt[N + nei[E + (i - E)]], 1);
}

// ============ exclusive scan over 2N counters ===============================
__global__ __launch_bounds__(256) void scan_partial_kernel(
    const int* __restrict__ cnt, int n, int* __restrict__ bsums)
{
    __shared__ int s[256];
    int t = threadIdx.x;
    int i0 = blockIdx.x * 1024 + t * 4;
    int e0 = (i0 + 0 < n) ? cnt[i0 + 0] : 0;
    int e1 = (i0 + 1 < n) ? cnt[i0 + 1] : 0;
    int e2 = (i0 + 2 < n) ? cnt[i0 + 2] : 0;
    int e3 = (i0 + 3 < n) ? cnt[i0 + 3] : 0;
    s[t] = e0 + e1 + e2 + e3;
    __syncthreads();
    for (int d = 128; d > 0; d >>= 1) {
        if (t < d) s[t] += s[t + d];
        __syncthreads();
    }
    if (t == 0) bsums[blockIdx.x] = s[0];
}

__global__ __launch_bounds__(256) void scan_bsums_kernel(int* __restrict__ bsums, int nb)
{
    __shared__ int s[256];
    int t = threadIdx.x;
    int v = (t < nb) ? bsums[t] : 0;
    s[t] = v;
    __syncthreads();
    for (int d = 1; d < 256; d <<= 1) {
        int u = (t >= d) ? s[t - d] : 0;
        __syncthreads();
        s[t] += u;
        __syncthreads();
    }
    if (t < nb) bsums[t] = s[t] - v;   // exclusive
}

__global__ __launch_bounds__(256) void scan_final_kernel(
    const int* __restrict__ cnt, int n, const int* __restrict__ bsums,
    int* __restrict__ offs, int* __restrict__ cursor)
{
    __shared__ int s[256];
    int t = threadIdx.x;
    int i0 = blockIdx.x * 1024 + t * 4;
    int e0 = (i0 + 0 < n) ? cnt[i0 + 0] : 0;
    int e1 = (i0 + 1 < n) ? cnt[i0 + 1] : 0;
    int e2 = (i0 + 2 < n) ? cnt[i0 + 2] : 0;
    int e3 = (i0 + 3 < n) ? cnt[i0 + 3] : 0;
    int mysum = e0 + e1 + e2 + e3;
    s[t] = mysum;
    __syncthreads();
    for (int d = 1; d < 256; d <<= 1) {
        int v = (t >= d) ? s[t - d] : 0;
        __syncthreads();
        s[t] += v;
        __syncthreads();
    }
    int base = bsums[blockIdx.x] + (s[t] - mysum);
    int o0 = base, o1 = base + e0, o2 = o1 + e1, o3 = o2 + e2;
    if (i0 + 0 < n) { offs[i0 + 0] = o0; cursor[i0 + 0] = o0; }
    if (i0 + 1 < n) { offs[i0 + 1] = o1; cursor[i0 + 1] = o1; }
    if (i0 + 2 < n) { offs[i0 + 2] = o2; cursor[i0 + 2] = o2; }
    if (i0 + 3 < n) { offs[i0 + 3] = o3; cursor[i0 + 3] = o3; }
}

// ============ place src ids into dst-sorted slots (both lists) ==============
__global__ __launch_bounds__(256) void place2_kernel(
    const int* __restrict__ pei, const int* __restrict__ nei, int E,
    int* __restrict__ cursor, int* __restrict__ ss, int N)
{
    int i = blockIdx.x * 256 + threadIdx.x;
    if (i < E) {
        int d = pei[E + i];
        ss[atomicAdd(&cursor[d], 1)] = pei[i];
    } else if (i < 2 * E) {
        int e = i - E;
        int d = nei[E + e];
        ss[atomicAdd(&cursor[N + d], 1)] = nei[e];
    }
}

// ============ aggregate: one wave per (node, half); bf16 gather, bf16 mean ==
__global__ __launch_bounds__(256) void agg_kernel(
    const int* __restrict__ ss, const int* __restrict__ offs,
    const int* __restrict__ cnt, int N, ushort* __restrict__ U)
{
    int w = blockIdx.x * 4 + (threadIdx.x >> 6);
    int lane = threadIdx.x & 63;
    if (w >= 2 * N) return;
    int node = (w < N) ? w : (w - N);
    int half = (w >= N) ? 1 : 0;
    int o0 = offs[w];
    int deg = cnt[w];
    int o1 = o0 + deg;

    float acc = 0.f;
    int i = o0;
    for (; i + 4 <= o1; i += 4) {
        int s0 = ss[i], s1 = ss[i + 1], s2 = ss[i + 2], s3 = ss[i + 3];
        float a = b2f(U[(size_t)s0 * 192 + 64 + lane]);
        float b = b2f(U[(size_t)s1 * 192 + 64 + lane]);
        float c = b2f(U[(size_t)s2 * 192 + 64 + lane]);
        float d = b2f(U[(size_t)s3 * 192 + 64 + lane]);
        acc += a; acc += b; acc += c; acc += d;
    }
    for (; i < o1; ++i) acc += b2f(U[(size_t)ss[i] * 192 + 64 + lane]);

    float mean = acc / fmaxf((float)deg, 1.f);
    U[(size_t)node * 192 + (half ? 128 : 0) + lane] = f2bf(mean);
}

// ============ MFMA transform: out = U-slices @ G + bias =====================
// U row = [aggp(0:64) | x(64:128) | aggn(128:192)] bf16.
// nh=0: out[:,0:64]  = U[:,0:128)  @ [Wp.T ; Wpc.T] + bp
// nh=1: out[:,64:128]= U[:,64:192) @ [Wnc.T; Wn.T ] + bn
__global__ __launch_bounds__(256) void transform_mfma_kernel(
    const ushort* __restrict__ U,
    const float* __restrict__ Wp, const float* __restrict__ Wpc, const float* __restrict__ bp,
    const float* __restrict__ Wn, const float* __restrict__ Wnc, const float* __restrict__ bn,
    int N, int ntiles, float* __restrict__ out)
{
    __shared__ __align__(16) ushort A[64][200];   // 64 nodes x 192 (+8 pad) bf16

    int t = threadIdx.x;
    int lane = t & 63;
    int w = t >> 6;       // wave 0..3
    int mh = w >> 1;      // node half: 32 nodes
    int nh = w & 1;       // output-column half
    int r16 = lane & 15;
    int q = lane >> 4;    // 0..3

    // --- B-frags (weights) into registers, once per block ---
    const float* W0 = nh ? Wnc : Wp;    // pairs with local k < 64
    const float* W1 = nh ? Wn  : Wpc;   // pairs with local k >= 64
    short8 bfrag[4][4];                 // [ki][ni]
    #pragma unroll
    for (int ki = 0; ki < 4; ++ki) {
        const float* Wsel = (ki < 2) ? W0 : W1;
        int kk = (ki * 32 + q * 8) & 63;
        #pragma unroll
        for (int ni = 0; ni < 4; ++ni) {
            int n = ni * 16 + r16;
            float4 f0 = *(const float4*)&Wsel[n * 64 + kk];
            float4 f1 = *(const float4*)&Wsel[n * 64 + kk + 4];
            short8 s;
            s[0] = (short)f2bf(f0.x); s[1] = (short)f2bf(f0.y);
            s[2] = (short)f2bf(f0.z); s[3] = (short)f2bf(f0.w);
            s[4] = (short)f2bf(f1.x); s[5] = (short)f2bf(f1.y);
            s[6] = (short)f2bf(f1.z); s[7] = (short)f2bf(f1.w);
            bfrag[ki][ni] = s;
        }
    }
    const float* bsel = nh ? bn : bp;
    float bias[4];
    #pragma unroll
    for (int ni = 0; ni < 4; ++ni) bias[ni] = bsel[ni * 16 + r16];

    int kbase = nh * 64;

    for (int tile = blockIdx.x; tile < ntiles; tile += gridDim.x) {
        int node0 = tile * 64;
        __syncthreads();   // protect LDS from previous iteration's readers
        // stage 64 rows x 384 B, coalesced 16 B chunks
        for (int i = t; i < 64 * 24; i += 256) {
            int row = i / 24, c = i % 24;
            int node = node0 + row;
            if (node >= N) node = N - 1;
            *(int4*)&A[row][c * 8] = *(const int4*)&U[(size_t)node * 192 + c * 8];
        }
        __syncthreads();

        f32x4 acc[2][4];
        #pragma unroll
        for (int mi = 0; mi < 2; ++mi)
            #pragma unroll
            for (int ni = 0; ni < 4; ++ni) {
                f32x4 c4 = {bias[ni], bias[ni], bias[ni], bias[ni]};
                acc[mi][ni] = c4;
            }

        #pragma unroll
        for (int ki = 0; ki < 4; ++ki) {
            short8 a0 = *(const short8*)&A[mh * 32 + r16][kbase + ki * 32 + q * 8];
            short8 a1 = *(const short8*)&A[mh * 32 + 16 + r16][kbase + ki * 32 + q * 8];
            #pragma unroll
            for (int ni = 0; ni < 4; ++ni) {
                acc[0][ni] = __builtin_amdgcn_mfma_f32_16x16x32_bf16(
                    a0, bfrag[ki][ni], acc[0][ni], 0, 0, 0);
                acc[1][ni] = __builtin_amdgcn_mfma_f32_16x16x32_bf16(
                    a1, bfrag[ki][ni], acc[1][ni], 0, 0, 0);
            }
        }

        #pragma unroll
        for (int mi = 0; mi < 2; ++mi)
            #pragma unroll
            for (int ni = 0; ni < 4; ++ni)
                #pragma unroll
                for (int r = 0; r < 4; ++r) {
                    int node = node0 + mh * 32 + mi * 16 + q * 4 + r;
                    if (node < N)
                        out[(size_t)node * 128 + nh * 64 + ni * 16 + r16] =
                            acc[mi][ni][r];
                }
    }
}

// ===================== f32 fallback path (small ws) =========================
__global__ __launch_bounds__(256) void scatter_kernel(
    const int* __restrict__ ei, int E, const float* __restrict__ x,
    float* __restrict__ out, int col_off, float* __restrict__ cnt)
{
    long long gid = (long long)blockIdx.x * 256 + threadIdx.x;
    int e = (int)(gid >> 6);
    if (e >= E) return;
    int f = (int)(gid & 63);
    int s = ei[e], d = ei[E + e];
    atomicAdd(&out[d * 128 + col_off + f], x[s * FDIM + f]);
    if (f == 0) atomicAdd(&cnt[d], 1.0f);
}

__global__ __launch_bounds__(256) void scale_kernel(
    float* __restrict__ out, const float* __restrict__ cnt, int N)
{
    int idx = blockIdx.x * 256 + threadIdx.x;
    if (idx >= N * 128) return;
    int node = idx >> 7, col = idx & 127, half = col >> 6;
    out[idx] /= fmaxf(cnt[half * N + node], 1.f);
}

__global__ __launch_bounds__(256) void transform_f32_kernel(
    const float* __restrict__ x,
    const float* __restrict__ Wp, const float* __restrict__ Wpc, const float* __restrict__ bp,
    const float* __restrict__ Wn, const float* __restrict__ Wnc, const float* __restrict__ bn,
    int N, float* __restrict__ out)
{
    __shared__ float V[2][128][64];
    __shared__ float B[192][NB + 4];
    __shared__ float bias[128];
    int t = threadIdx.x;
    int node0 = blockIdx.x * NB;
    for (int i = t; i < 4096; i += 256) {
        int k = i >> 6, j = i & 63;
        V[0][k][j]      = Wp[j * 64 + k];
        V[0][64 + k][j] = Wpc[j * 64 + k];
        V[1][k][j]      = Wnc[j * 64 + k];
        V[1][64 + k][j] = Wn[j * 64 + k];
    }
    if (t < 64) { bias[t] = bp[t]; bias[64 + t] = bn[t]; }
    for (int i = t; i < 64 * NB; i += 256) {
        int k = i & 63, n = i >> 6;
        int node = node0 + n;
        if (node < N) {
            B[k][n]       = out[(size_t)node * 128 + k];
            B[64 + k][n]  = x[node * 64 + k];
            B[128 + k][n] = out[(size_t)node * 128 + 64 + k];
        }
    }
    __syncthreads();
    int jj = t & 31, nq = t >> 5;
    float acc[2][4][2];
    for (int h = 0; h < 2; ++h)
        for (int i = 0; i < 4; ++i) { acc[h][i][0] = 0.f; acc[h][i][1] = 0.f; }
    for (int h = 0; h < 2; ++h) {
        int browbase = h * 64;
        #pragma unroll 4
        for (int kk = 0; kk < 128; ++kk) {
            float2 v = *(const float2*)&V[h][kk][2 * jj];
            float4 b = *(const float4*)&B[browbase + kk][4 * nq];
            acc[h][0][0] += b.x * v.x;  acc[h][0][1] += b.x * v.y;
            acc[h][1][0] += b.y * v.x;  acc[h][1][1] += b.y * v.y;
            acc[h][2][0] += b.z * v.x;  acc[h][2][1] += b.z * v.y;
            acc[h][3][0] += b.w * v.x;  acc[h][3][1] += b.w * v.y;
        }
    }
    for (int h = 0; h < 2; ++h) {
        float bx = bias[h * 64 + 2 * jj], by = bias[h * 64 + 2 * jj + 1];
        for (int i = 0; i < 4; ++i) {
            int node = node0 + 4 * nq + i;
            if (node < N) {
                float2 r; r.x = acc[h][i][0] + bx; r.y = acc[h][i][1] + by;
                *(float2*)&out[(size_t)node * 128 + h * 64 + 2 * jj] = r;
            }
        }
    }
}

// ============================================================================
extern "C" void kernel_launch(void* const* d_in, const int* in_sizes, int n_in,
                              void* d_out, int out_size, void* d_ws, size_t ws_size,
                              hipStream_t stream) {
    const float* x   = (const float*)d_in[0];
    const int*   pei = (const int*)d_in[1];
    const int*   nei = (const int*)d_in[2];
    const float* Wp  = (const float*)d_in[3];
    const float* Wpc = (const float*)d_in[4];
    const float* bp  = (const float*)d_in[5];
    const float* Wn  = (const float*)d_in[6];
    const float* Wnc = (const float*)d_in[7];
    const float* bn  = (const float*)d_in[8];
    float* out = (float*)d_out;

    int N = in_sizes[0] / FDIM;
    int E = in_sizes[1] / 2;
    int n2 = 2 * N;
    int nb = (n2 + 1023) / 1024;

    size_t ints_need = (size_t)3 * n2 + 4096 + (size_t)2 * E;
    size_t U_off = ((ints_need * 4 + 15) / 16) * 16;
    size_t need = U_off + (size_t)N * 192 * 2;

    if (ws_size >= need && nb <= 256) {
        int* cnt    = (int*)d_ws;
        int* offs   = cnt + n2;
        int* cursor = offs + n2;
        int* bsums  = cursor + n2;
        int* ss     = bsums + 4096;
        ushort* U   = (ushort*)((char*)d_ws + U_off);

        hipMemsetAsync(cnt, 0, (size_t)n2 * sizeof(int), stream);

        prep_kernel<<<(N * 64 / 4 + 255) / 256, 256, 0, stream>>>(x, N, U);

        int eb2 = (2 * E + 255) / 256;
        hist2_kernel<<<eb2, 256, 0, stream>>>(pei, nei, E, cnt, N);

        scan_partial_kernel<<<nb, 256, 0, stream>>>(cnt, n2, bsums);
        scan_bsums_kernel<<<1, 256, 0, stream>>>(bsums, nb);
        scan_final_kernel<<<nb, 256, 0, stream>>>(cnt, n2, bsums, offs, cursor);

        place2_kernel<<<eb2, 256, 0, stream>>>(pei, nei, E, cursor, ss, N);

        agg_kernel<<<(n2 + 3) / 4, 256, 0, stream>>>(ss, offs, cnt, N, U);

        int ntiles = (N + 63) / 64;
        transform_mfma_kernel<<<768, 256, 0, stream>>>(
            U, Wp, Wpc, bp, Wn, Wnc, bn, N, ntiles, out);
    } else {
        float* cntf = (float*)d_ws;
        hipMemsetAsync(d_out, 0, (size_t)out_size * sizeof(float), stream);
        hipMemsetAsync(d_ws, 0, (size_t)n2 * sizeof(float), stream);
        int sblocks = (int)(((long long)E * 64 + 255) / 256);
        scatter_kernel<<<sblocks, 256, 0, stream>>>(pei, E, x, out, 0, cntf);
        scatter_kernel<<<sblocks, 256, 0, stream>>>(nei, E, x, out, 64, cntf + N);
        scale_kernel<<<(N * 128 + 255) / 256, 256, 0, stream>>>(out, cntf, N);
        transform_f32_kernel<<<(N + NB - 1) / NB, 256, 0, stream>>>(
            x, Wp, Wpc, bp, Wn, Wnc, bn, N, out);
    }
}